// Round 1
// baseline (109.657 us; speedup 1.0000x reference)
//
#include <hip/hip_runtime.h>

// Problem: out[i] = sum_k targets[i,k] * temporal_bases[batch_indices[1],k] * scaling[k]
// B=8192, K=1024, T=16384. Pure matvec; memory-bound on the 33.6 MB `targets` read.

#define KDIM 1024

__global__ __launch_bounds__(256) void recompose_col1_kernel(
    const float* __restrict__ targets,        // (B, K)
    const float* __restrict__ temporal_bases, // (T, K)
    const float* __restrict__ scaling,        // (K,)
    const int*   __restrict__ batch_indices,  // (B,)
    float*       __restrict__ out)            // (B,)
{
    const int wave = threadIdx.x >> 6;   // 0..3, one wave per row
    const int lane = threadIdx.x & 63;
    const int row  = (blockIdx.x << 2) + wave;

    const long long sel = (long long)batch_indices[1];
    const float* __restrict__ wrow = temporal_bases + sel * (long long)KDIM;
    const float* __restrict__ trow = targets + (long long)row * (long long)KDIM;

    float acc = 0.0f;
    // lane l, step j reads float4 at k = j*256 + l*4 -> each load instruction
    // is a contiguous 64 lanes x 16 B = 1 KiB coalesced segment.
    #pragma unroll
    for (int j = 0; j < 4; ++j) {
        const int k = (j << 8) + (lane << 2);
        const float4 a = *(const float4*)(trow + k);
        const float4 b = *(const float4*)(wrow + k);
        const float4 s = *(const float4*)(scaling + k);
        acc += a.x * b.x * s.x;
        acc += a.y * b.y * s.y;
        acc += a.z * b.z * s.z;
        acc += a.w * b.w * s.w;
    }

    // 64-lane wave reduction
    #pragma unroll
    for (int off = 32; off > 0; off >>= 1)
        acc += __shfl_down(acc, off, 64);

    if (lane == 0) out[row] = acc;
}

extern "C" void kernel_launch(void* const* d_in, const int* in_sizes, int n_in,
                              void* d_out, int out_size, void* d_ws, size_t ws_size,
                              hipStream_t stream) {
    const float* targets        = (const float*)d_in[0];
    const float* temporal_bases = (const float*)d_in[1];
    const float* scaling        = (const float*)d_in[2];
    const int*   batch_indices  = (const int*)d_in[3];
    float*       out            = (float*)d_out;

    const int B = in_sizes[0] / KDIM;          // 8192
    const int blocks = B / 4;                  // 4 rows (waves) per block
    recompose_col1_kernel<<<blocks, 256, 0, stream>>>(
        targets, temporal_bases, scaling, batch_indices, out);
}